// Round 7
// baseline (335.527 us; speedup 1.0000x reference)
//
#include <hip/hip_runtime.h>
#include <hip/hip_bf16.h>
#include <math.h>

#define DEVINL __device__ __forceinline__

// Runtime-dtype load for EXTERNAL tensors: bf=1 -> bf16, bf=0 -> f32.
DEVINL float loadIn(const void* p, long i, int bf) {
    return bf ? __bfloat162float(((const __hip_bfloat16*)p)[i])
              : ((const float*)p)[i];
}

DEVINL float leaky(float v) { return fmaxf(v, 0.2f * v); }  // branch-free

DEVINL unsigned pack_bf16(float a, float b) {
    __hip_bfloat16 x = __float2bfloat16(a), y = __float2bfloat16(b);
    unsigned short ux = *reinterpret_cast<unsigned short*>(&x);
    unsigned short uy = *reinterpret_cast<unsigned short*>(&y);
    return (unsigned)ux | ((unsigned)uy << 16);
}
DEVINL float lo16(unsigned u) { return __uint_as_float(u << 16); }
DEVINL float hi16(unsigned u) { return __uint_as_float(u & 0xFFFF0000u); }

// ---------------------------------------------------------------------------
// prep: fused dtype sniffer (proven R2-R12) + bcnt zeroing. One block.
// ---------------------------------------------------------------------------
__global__ __launch_bounds__(1024) void prep(const unsigned* __restrict__ x,
                                             int* __restrict__ flag,
                                             int* __restrict__ bcnt) {
    __shared__ int sh[1024];
    int t = threadIdx.x;
    bcnt[t] = 0;
    int cnt = 0;
    for (int i = t; i < 2048; i += 1024) {
        unsigned ex = (x[i] >> 7) & 0xFFu;
        if (ex >= 110u && ex <= 140u) cnt++;
    }
    sh[t] = cnt;
    __syncthreads();
    for (int s = 512; s > 0; s >>= 1) {
        if (t < s) sh[t] += sh[t + s];
        __syncthreads();
    }
    if (t == 0) *flag = (sh[0] >= 1200) ? 1 : 0;
}

// ---------------------------------------------------------------------------
// Two-level CSR build. Bucket = dst >> 8 (256 nodes/bucket — R12 proven).
// ---------------------------------------------------------------------------
__global__ __launch_bounds__(256) void bhist(const int* __restrict__ dst, int E,
                                             int* __restrict__ bcnt) {
    __shared__ int lh[512];
    for (int i = threadIdx.x; i < 512; i += 256) lh[i] = 0;
    __syncthreads();
    int stride = gridDim.x * 256;
    for (int e = blockIdx.x * 256 + threadIdx.x; e < E; e += stride)
        atomicAdd(&lh[dst[e] >> 8], 1);
    __syncthreads();
    for (int i = threadIdx.x; i < 512; i += 256)
        if (lh[i]) atomicAdd(&bcnt[i], lh[i]);
}

__global__ __launch_bounds__(1024) void bscan(const int* __restrict__ bcnt,
                                              int* __restrict__ bstart,
                                              int* __restrict__ bcur) {
    __shared__ int sA[1024], sB[1024];
    int t = threadIdx.x;
    int c = bcnt[t];
    sA[t] = c;
    __syncthreads();
    int* a = sA; int* b = sB;
    for (int off = 1; off < 1024; off <<= 1) {
        int v = a[t] + ((t >= off) ? a[t - off] : 0);
        __syncthreads();
        b[t] = v;
        __syncthreads();
        int* tp = a; a = b; b = tp;
    }
    int excl = a[t] - c;
    bstart[t] = excl;
    bcur[t] = excl;
    if (t == 1023) bstart[1024] = a[t];
}

// Block-aggregated reservation scatter (R13 proven).
#define CS_CHUNK 16384
__global__ __launch_bounds__(512) void block_scatter(
    const int* __restrict__ srcIdx, const int* __restrict__ dstIdx, int E,
    int* __restrict__ bcur, int* __restrict__ buf) {
    __shared__ int lh[512];
    __shared__ int lcur[512];
    int t = threadIdx.x;
    int e0 = blockIdx.x * CS_CHUNK;
    int e1 = e0 + CS_CHUNK; if (e1 > E) e1 = E;

    if (t < 512) lh[t] = 0;
    __syncthreads();
    for (int e = e0 + t; e < e1; e += 512)
        atomicAdd(&lh[dstIdx[e] >> 8], 1);
    __syncthreads();
    if (t < 512) {
        int c = lh[t];
        lcur[t] = c ? atomicAdd(&bcur[t], c) : 0;
    }
    __syncthreads();
    for (int e = e0 + t; e < e1; e += 512) {
        int d = dstIdx[e];
        int s = srcIdx[e];
        int pos = atomicAdd(&lcur[d >> 8], 1);
        buf[pos] = ((d & 255) << 17) | s;   // src < 2^17 (N=1e5)
    }
}

// fine_scatter (R12 proven): one block per 256-node bucket.
#define FS_CAP 10240
__global__ __launch_bounds__(256) void fine_scatter(
    const int* __restrict__ bstart, int* buf, int* ss,
    int* __restrict__ rp, int* __restrict__ cnt, int N) {
    __shared__ int stage[FS_CAP];
    __shared__ int hcnt[256];
    __shared__ int hA[256], hB[256];
    __shared__ int lcur[256];
    int bkt = blockIdx.x;
    int t = threadIdx.x;
    int s0 = bstart[bkt];
    int m = bstart[bkt + 1] - s0;
    if (m > FS_CAP) m = FS_CAP;

    for (int i = t; i < m; i += 256) stage[i] = buf[s0 + i];
    hcnt[t] = 0;
    __syncthreads();
    for (int i = t; i < m; i += 256) atomicAdd(&hcnt[stage[i] >> 17], 1);
    __syncthreads();
    hA[t] = hcnt[t];
    __syncthreads();
    int* a = hA; int* b = hB;
    for (int off = 1; off < 256; off <<= 1) {
        int v = a[t] + ((t >= off) ? a[t - off] : 0);
        __syncthreads();
        b[t] = v;
        __syncthreads();
        int* tp = a; a = b; b = tp;
    }
    {
        int excl = a[t] - hcnt[t];
        lcur[t] = s0 + excl;
        int node = bkt * 256 + t;
        if (node < N) {
            rp[node] = s0 + excl;
            cnt[node] = hcnt[t];
        }
    }
    __syncthreads();
    for (int i = t; i < m; i += 256) {
        int v = stage[i];
        int pos = atomicAdd(&lcur[v >> 17], 1);
        ss[pos] = v & 0x1FFFF;
    }
}

// ---------------------------------------------------------------------------
// xprep (R17 proven): pad x -> xp[N][4] f32 + commuted attention vectors.
// ---------------------------------------------------------------------------
__global__ __launch_bounds__(256) void xprep(
    const void* __restrict__ x, const int* __restrict__ flagp,
    const void* __restrict__ W1, const void* __restrict__ as1,
    const void* __restrict__ ad1,
    float4* __restrict__ xp, float* __restrict__ cvec, int N)
{
    const int bf = *flagp;
    int n = blockIdx.x * 256 + threadIdx.x;
    if (n < N) {
        float4 v;
        v.x = loadIn(x, (long)n * 3 + 0, bf);
        v.y = loadIn(x, (long)n * 3 + 1, bf);
        v.z = loadIn(x, (long)n * 3 + 2, bf);
        v.w = 0.0f;
        xp[n] = v;
    }
    if (blockIdx.x == 0 && threadIdx.x < 12) {
        int t = threadIdx.x;
        int isd = t >= 6;
        int h = (t - 6 * isd) / 3;
        int k = (t - 6 * isd) % 3;
        const void* av = isd ? ad1 : as1;
        float s = 0.0f;
        for (int c = 0; c < 16; c++)
            s += loadIn(W1, k * 32 + h * 16 + c, bf) * loadIn(av, h * 16 + c, bf);
        cvec[t] = s;
    }
}

// ---------------------------------------------------------------------------
// aggregate_l1 (R17 proven): commuted layer-1 GAT, 16B/edge gather.
// ---------------------------------------------------------------------------
__global__ __launch_bounds__(256) void aggregate_l1(
    const int* __restrict__ rp_start, const int* __restrict__ cnt,
    const int* __restrict__ ss, const float4* __restrict__ xp,
    const float* __restrict__ cvec,
    const void* __restrict__ W1, const void* __restrict__ b1,
    const int* __restrict__ flagp,
    unsigned* __restrict__ xout, int N)
{
    const int bf = *flagp;
    __shared__ float Wl[96];
    __shared__ float bl[32];
    for (int i = threadIdx.x; i < 96; i += 256) Wl[i] = loadIn(W1, i, bf);
    for (int i = threadIdx.x; i < 32; i += 256) bl[i] = loadIn(b1, i, bf);
    __syncthreads();

    int lane = threadIdx.x & 63;
    int g = lane >> 4;
    int q = lane & 15;
    int wid = threadIdx.x >> 6;

    float cs[2][3], cd[2][3];
#pragma unroll
    for (int h = 0; h < 2; h++)
#pragma unroll
        for (int k = 0; k < 3; k++) {
            cs[h][k] = cvec[h * 3 + k];
            cd[h][k] = cvec[6 + h * 3 + k];
        }

    const int nstride = gridDim.x * 16;
    for (int node = blockIdx.x * 16 + wid * 4 + g; ; node += nstride) {
        if (node - g >= N) break;
        bool valid = node < N;
        int idx = valid ? node : 0;
        int start = rp_start[idx];
        int deg = valid ? cnt[idx] : 0;
        float4 xn = xp[idx];

        float alsn[2], aldn[2];
#pragma unroll
        for (int h = 0; h < 2; h++) {
            alsn[h] = xn.x * cs[h][0] + xn.y * cs[h][1] + xn.z * cs[h][2];
            aldn[h] = xn.x * cd[h][0] + xn.y * cd[h][1] + xn.z * cd[h][2];
        }

        float a00 = 0.f, a01 = 0.f, a02 = 0.f, s0 = 0.f;
        float a10 = 0.f, a11 = 0.f, a12 = 0.f, s1 = 0.f;

        if (q == 0 && valid) {
            float e0 = __expf(fminf(leaky(alsn[0] + aldn[0]), 80.0f));
            float e1 = __expf(fminf(leaky(alsn[1] + aldn[1]), 80.0f));
            a00 = e0 * xn.x; a01 = e0 * xn.y; a02 = e0 * xn.z; s0 = e0;
            a10 = e1 * xn.x; a11 = e1 * xn.y; a12 = e1 * xn.z; s1 = e1;
        }

        for (int kb = q; kb < deg; kb += 32) {
            int k2 = kb + 16;
            bool ok2 = k2 < deg;
            int sA = ss[start + kb];
            int sB = ss[start + (ok2 ? k2 : kb)];
            float4 xa = xp[sA];
            float4 xb = xp[sB];
            {
                float l0 = xa.x * cs[0][0] + xa.y * cs[0][1] + xa.z * cs[0][2] + aldn[0];
                float l1 = xa.x * cs[1][0] + xa.y * cs[1][1] + xa.z * cs[1][2] + aldn[1];
                float e0 = __expf(fminf(leaky(l0), 80.0f));
                float e1 = __expf(fminf(leaky(l1), 80.0f));
                a00 = fmaf(xa.x, e0, a00); a01 = fmaf(xa.y, e0, a01);
                a02 = fmaf(xa.z, e0, a02); s0 += e0;
                a10 = fmaf(xa.x, e1, a10); a11 = fmaf(xa.y, e1, a11);
                a12 = fmaf(xa.z, e1, a12); s1 += e1;
            }
            {
                float l0 = xb.x * cs[0][0] + xb.y * cs[0][1] + xb.z * cs[0][2] + aldn[0];
                float l1 = xb.x * cs[1][0] + xb.y * cs[1][1] + xb.z * cs[1][2] + aldn[1];
                float e0 = ok2 ? __expf(fminf(leaky(l0), 80.0f)) : 0.0f;
                float e1 = ok2 ? __expf(fminf(leaky(l1), 80.0f)) : 0.0f;
                a00 = fmaf(xb.x, e0, a00); a01 = fmaf(xb.y, e0, a01);
                a02 = fmaf(xb.z, e0, a02); s0 += e0;
                a10 = fmaf(xb.x, e1, a10); a11 = fmaf(xb.y, e1, a11);
                a12 = fmaf(xb.z, e1, a12); s1 += e1;
            }
        }

#pragma unroll
        for (int off = 1; off < 16; off <<= 1) {
            a00 += __shfl_xor(a00, off, 64); a01 += __shfl_xor(a01, off, 64);
            a02 += __shfl_xor(a02, off, 64); s0  += __shfl_xor(s0,  off, 64);
            a10 += __shfl_xor(a10, off, 64); a11 += __shfl_xor(a11, off, 64);
            a12 += __shfl_xor(a12, off, 64); s1  += __shfl_xor(s1,  off, 64);
        }

        if (valid) {
            int h = q >> 3;
            float inv = 1.0f / ((h ? s1 : s0) + 1e-16f);
            float g0 = (h ? a10 : a00) * inv;
            float g1 = (h ? a11 : a01) * inv;
            float g2 = (h ? a12 : a02) * inv;
            int c0 = 2 * q;
            float v0 = g0 * Wl[c0]      + g1 * Wl[32 + c0]      + g2 * Wl[64 + c0]      + bl[c0];
            float v1 = g0 * Wl[c0 + 1]  + g1 * Wl[32 + c0 + 1]  + g2 * Wl[64 + c0 + 1]  + bl[c0 + 1];
            v0 = v0 > 0.0f ? v0 : __expf(fminf(v0, 0.0f)) - 1.0f;
            v1 = v1 > 0.0f ? v1 : __expf(fminf(v1, 0.0f)) - 1.0f;
            xout[(long)node * 16 + q] = pack_bf16(v0, v1);
        }
    }
}

// ---------------------------------------------------------------------------
// node_transform (R9/R1 proven, node-major). Layers 2-3 only.
// ---------------------------------------------------------------------------
template <int XMODE, int C_IN, int H, int C>
__global__ __launch_bounds__(256) void node_transform(
    const void* __restrict__ xin, const int* __restrict__ flagp,
    const void* __restrict__ W, const void* __restrict__ a_s,
    const void* __restrict__ a_d,
    unsigned* __restrict__ h2, float* __restrict__ als,
    float* __restrict__ ald, int N)
{
    const int bf = *flagp;
    constexpr int HC = H * C;
    __shared__ float Ws[C_IN * HC];
    __shared__ float asS[HC];
    __shared__ float adS[HC];
    for (int i = threadIdx.x; i < C_IN * HC; i += 256) Ws[i] = loadIn(W, i, bf);
    for (int i = threadIdx.x; i < HC; i += 256) {
        asS[i] = loadIn(a_s, i, bf);
        adS[i] = loadIn(a_d, i, bf);
    }
    __syncthreads();

    int n = blockIdx.x * 256 + threadIdx.x;
    if (n >= N) return;

    float xv[C_IN];
    if (XMODE) {
        const uint4* x4 = (const uint4*)xin;
#pragma unroll
        for (int q = 0; q < C_IN / 8; q++) {
            uint4 w = x4[(long)n * (C_IN / 8) + q];
            xv[q * 8 + 0] = lo16(w.x); xv[q * 8 + 1] = hi16(w.x);
            xv[q * 8 + 2] = lo16(w.y); xv[q * 8 + 3] = hi16(w.y);
            xv[q * 8 + 4] = lo16(w.z); xv[q * 8 + 5] = hi16(w.z);
            xv[q * 8 + 6] = lo16(w.w); xv[q * 8 + 7] = hi16(w.w);
        }
    } else {
#pragma unroll
        for (int k = 0; k < C_IN; k++) xv[k] = loadIn(xin, (long)n * C_IN + k, bf);
    }

    float hv[HC];
#pragma unroll
    for (int j = 0; j < HC; j++) {
        float v = 0.0f;
#pragma unroll
        for (int k = 0; k < C_IN; k++) v = fmaf(xv[k], Ws[k * HC + j], v);
        hv[j] = v;
    }
#pragma unroll
    for (int jj = 0; jj < HC / 2; jj++)
        h2[(long)n * (HC / 2) + jj] = pack_bf16(hv[2 * jj], hv[2 * jj + 1]);

#pragma unroll
    for (int hh = 0; hh < H; hh++) {
        float vs = 0.0f, vd = 0.0f;
#pragma unroll
        for (int c = 0; c < C; c++) {
            vs = fmaf(hv[hh * C + c], asS[hh * C + c], vs);
            vd = fmaf(hv[hh * C + c], adS[hh * C + c], vd);
        }
        als[(long)n * H + hh] = vs;
        ald[(long)n * H + hh] = vd;
    }
}

// ---------------------------------------------------------------------------
// aggregate (R20 = R18 geometry + gates): R6 post-mortem proved the kernel is
// MLP-limited (NCH=8 halved in-flight gathers 18->9: VALUBusy 73->55%, time
// 62->72us). So: keep R18/R5 geometry (NCH=4/J=8/EPW=8/UNR=6 for l2 -> 18
// loads in flight), and add ONLY issue-diet that doesn't shrink useful MLP:
//  - deg-gated units: units with u*EPW >= deg issued DUPLICATE-address loads
//    (L1 hits: issue+TA cost, zero latency coverage). Gating them (mean deg
//    33 -> ~4.6/6 units active) cuts ~23% of unit issue, keeps all useful
//    loads. Gate applied identically at issue and compute (no uninit-reg
//    hazard; deg=0 nodes touch nothing, self-loop still runs).
//  - scalar CSR: readfirstlane(node) -> rp/cnt via s_load; nd/st/dg in SGPR
//    so the gates are s_cbranch (scalar), not exec churn.
// VGPR must stay <=64 (waves/CU halves at 64 — m69); R18 was 48.
// ---------------------------------------------------------------------------
template <int H, int C, int NCH, int UNR, int FUSE>
__global__ __launch_bounds__(256) void aggregate(
    const int* __restrict__ rp_start, const int* __restrict__ cnt,
    const int* __restrict__ ss,
    const unsigned* __restrict__ h2,
    const float* __restrict__ als, const float* __restrict__ ald,
    const void* __restrict__ bias, const void* __restrict__ Wo,
    const void* __restrict__ bo, const int* __restrict__ flagp,
    void* __restrict__ xout, int N)
{
    constexpr int HC = H * C;
    constexpr int J = HC / NCH;     // lanes per edge row
    constexpr int EPW = 64 / J;     // edge rows per wave
    constexpr int SLOTS = UNR * EPW;
    const int bf = *flagp;
    int lane = threadIdx.x & 63;
    int p = lane / J;
    int j = lane % J;
    int c0 = NCH * j;
    int head = c0 / C;
    const float* __restrict__ alsH = als + head;

    float bv[NCH];
#pragma unroll
    for (int i = 0; i < NCH; i++) bv[i] = loadIn(bias, c0 + i, bf);
    float wov[NCH];
    float bov = 0.0f;
    if constexpr (FUSE) {
#pragma unroll
        for (int i = 0; i < NCH; i++) wov[i] = loadIn(Wo, c0 + i, bf);
        bov = loadIn(bo, 0, bf);
    }

    const int nstride = gridDim.x << 2;   // 4 waves per block
    const int node0 = (blockIdx.x << 2) + (threadIdx.x >> 6);
    if (node0 >= N) return;

    // ---- pipeline state: 2 slots, all statically indexed (rule #20)
    int nd0, nd1, st0, st1, dg0, dg1;
    float an0, an1, sa0, sa1;
    uint2 sq0, sq1; unsigned sw0, sw1;           // self h row fragments
    int sr0[UNR], sr1[UNR];
    float av0[UNR], av1[UNR];
    uint2 hq0[UNR], hq1[UNR];
    unsigned hw0[UNR], hw1[UNR];

#define AGG_LOADCSR(S, NODE) {                                              \
    int nn_ = (NODE); nd##S = nn_;                                          \
    int ii_ = __builtin_amdgcn_readfirstlane(nn_ < N ? nn_ : N - 1);        \
    st##S = rp_start[ii_];                                                  \
    dg##S = nn_ < N ? cnt[ii_] : 0;                                         \
    an##S = ald[ii_ * H + head];                                            \
    sa##S = alsH[ii_ * H];                                                  \
    if constexpr (NCH == 4) sq##S = ((const uint2*)h2)[ii_ * (HC / 4) + j]; \
    else sw##S = h2[ii_ * (HC / 2) + j]; }

#define AGG_ISSUE_SS(S) {                                                   \
    _Pragma("unroll") for (int u = 0; u < UNR; u++) {                       \
        if (u * EPW < dg##S) {          /* scalar gate: dg in SGPR */       \
            int k_ = p + u * EPW;                                           \
            sr##S[u] = ss[st##S + (k_ < dg##S ? k_ : dg##S - 1)];           \
        } else sr##S[u] = 0; } }

#define AGG_ISSUE_G(S) {                                                    \
    _Pragma("unroll") for (int u = 0; u < UNR; u++) {                       \
        if (u * EPW < dg##S) {                                              \
            av##S[u] = alsH[sr##S[u] * H];                                  \
            if constexpr (NCH == 4)                                         \
                hq##S[u] = ((const uint2*)h2)[sr##S[u] * (HC / 4) + j];     \
            else hw##S[u] = h2[sr##S[u] * (HC / 2) + j];                    \
        } } }

#define AGG_BODY(A, B) {                                                    \
    int node_c = nd##A, start_c = st##A, deg_c = dg##A;                     \
    float an_c = an##A, sa_c = sa##A;                                       \
    uint2 sq_c = sq##A; unsigned sw_c = sw##A; (void)sq_c; (void)sw_c;      \
    /* (a) issue gathers for NXT (gated by its deg) */                      \
    AGG_ISSUE_G(B);                                                         \
    /* (b) prefetch CSR+self for node_c + 2*nstride into slot A */          \
    AGG_LOADCSR(A, node_c + 2 * nstride);                                   \
    /* (c) compute CUR */                                                   \
    float acc[NCH]; float ssum = 0.0f;                                      \
    _Pragma("unroll") for (int i = 0; i < NCH; i++) acc[i] = 0.0f;          \
    if (p == 0) {                                                           \
        float es_ = __expf(fminf(leaky(sa_c + an_c), 80.0f));               \
        if constexpr (NCH == 4) {                                           \
            acc[0] = lo16(sq_c.x) * es_; acc[1] = hi16(sq_c.x) * es_;       \
            acc[2] = lo16(sq_c.y) * es_; acc[3] = hi16(sq_c.y) * es_;       \
        } else {                                                            \
            acc[0] = lo16(sw_c) * es_; acc[1] = hi16(sw_c) * es_;           \
        }                                                                   \
        ssum = es_;                                                         \
    }                                                                       \
    _Pragma("unroll") for (int u = 0; u < UNR; u++) {                       \
        if (u * EPW < deg_c) {          /* same gate as at issue time */    \
            int k_ = p + u * EPW;                                           \
            float e_ = (k_ < deg_c)                                         \
                ? __expf(fminf(leaky(av##A[u] + an_c), 80.0f)) : 0.0f;      \
            if constexpr (NCH == 4) {                                       \
                acc[0] = fmaf(lo16(hq##A[u].x), e_, acc[0]);                \
                acc[1] = fmaf(hi16(hq##A[u].x), e_, acc[1]);                \
                acc[2] = fmaf(lo16(hq##A[u].y), e_, acc[2]);                \
                acc[3] = fmaf(hi16(hq##A[u].y), e_, acc[3]);                \
            } else {                                                        \
                acc[0] = fmaf(lo16(hw##A[u]), e_, acc[0]);                  \
                acc[1] = fmaf(hi16(hw##A[u]), e_, acc[1]);                  \
            }                                                               \
            ssum += e_;                                                     \
        }                                                                   \
    }                                                                       \
    /* rare tail: deg > SLOTS (scalar branch) */                            \
    if (deg_c > SLOTS) {                                                    \
        for (int kb_ = SLOTS + p; kb_ < deg_c; kb_ += EPW) {                \
            int s_ = ss[start_c + kb_];                                     \
            float e_ = __expf(fminf(leaky(alsH[s_ * H] + an_c), 80.0f));    \
            if constexpr (NCH == 4) {                                       \
                uint2 hv_ = ((const uint2*)h2)[s_ * (HC / 4) + j];          \
                acc[0] = fmaf(lo16(hv_.x), e_, acc[0]);                     \
                acc[1] = fmaf(hi16(hv_.x), e_, acc[1]);                     \
                acc[2] = fmaf(lo16(hv_.y), e_, acc[2]);                     \
                acc[3] = fmaf(hi16(hv_.y), e_, acc[3]);                     \
            } else {                                                        \
                unsigned hv_ = h2[s_ * (HC / 2) + j];                       \
                acc[0] = fmaf(lo16(hv_), e_, acc[0]);                       \
                acc[1] = fmaf(hi16(hv_), e_, acc[1]);                       \
            }                                                               \
            ssum += e_;                                                     \
        }                                                                   \
    }                                                                       \
    /* (e) issue ss for N2 (CSR slot A landed during compute) */            \
    AGG_ISSUE_SS(A);                                                        \
    /* (d) finish CUR */                                                    \
    _Pragma("unroll") for (int off = J; off < 64; off <<= 1) {              \
        _Pragma("unroll") for (int i = 0; i < NCH; i++)                     \
            acc[i] += __shfl_xor(acc[i], off, 64);                          \
        ssum += __shfl_xor(ssum, off, 64);                                  \
    }                                                                       \
    float inv = 1.0f / (ssum + 1e-16f);                                     \
    float v[NCH];                                                           \
    _Pragma("unroll") for (int i = 0; i < NCH; i++) {                       \
        float t_ = acc[i] * inv + bv[i];                                    \
        v[i] = t_ > 0.0f ? t_ : __expf(fminf(t_, 0.0f)) - 1.0f;             \
    }                                                                       \
    if constexpr (FUSE) {                                                   \
        float r_ = 0.0f;                                                    \
        _Pragma("unroll") for (int i = 0; i < NCH; i++)                     \
            r_ = fmaf(v[i], wov[i], r_);                                    \
        _Pragma("unroll") for (int off = 1; off < J; off <<= 1)             \
            r_ += __shfl_xor(r_, off, 64);                                  \
        if (lane == 0 && node_c < N) {                                      \
            r_ += bov;                                                      \
            if (bf) ((__hip_bfloat16*)xout)[node_c] = __float2bfloat16(r_); \
            else    ((float*)xout)[node_c] = r_;                            \
        }                                                                   \
    } else {                                                                \
        if (p == 0 && node_c < N) {                                         \
            if constexpr (NCH == 4) {                                       \
                uint2 o_; o_.x = pack_bf16(v[0], v[1]);                     \
                o_.y = pack_bf16(v[2], v[3]);                               \
                ((uint2*)xout)[node_c * (HC / 4) + j] = o_;                 \
            } else {                                                        \
                ((unsigned*)xout)[node_c * (HC / 2) + j] =                  \
                    pack_bf16(v[0], v[1]);                                  \
            }                                                               \
        }                                                                   \
    } }

    // ---- prologue: fill slots 0 (node0) and 1 (node0+ns)
    AGG_LOADCSR(0, node0);
    AGG_LOADCSR(1, node0 + nstride);
    AGG_ISSUE_SS(0);
    AGG_ISSUE_G(0);
    AGG_ISSUE_SS(1);

    for (;;) {
        AGG_BODY(0, 1);
        if (nd1 >= N) break;
        AGG_BODY(1, 0);
        if (nd0 >= N) break;
    }

#undef AGG_LOADCSR
#undef AGG_ISSUE_SS
#undef AGG_ISSUE_G
#undef AGG_BODY
}

// ---------------------------------------------------------------------------
extern "C" void kernel_launch(void* const* d_in, const int* in_sizes, int n_in,
                              void* d_out, int out_size, void* d_ws, size_t ws_size,
                              hipStream_t stream) {
    const void* x   = d_in[0];
    const int*  ei  = (const int*)d_in[1];
    const void* W1  = d_in[2];
    const void* as1 = d_in[3];
    const void* ad1 = d_in[4];
    const void* b1  = d_in[5];
    const void* W2  = d_in[6];
    const void* as2 = d_in[7];
    const void* ad2 = d_in[8];
    const void* b2  = d_in[9];
    const void* W3  = d_in[10];
    const void* as3 = d_in[11];
    const void* ad3 = d_in[12];
    const void* b3  = d_in[13];
    const void* Wo  = d_in[14];
    const void* bo  = d_in[15];

    const int N = in_sizes[0] / 3;
    const int E = in_sizes[1] / 2;
    const int* ei0 = ei;       // src
    const int* ei1 = ei + E;   // dst

    // ---- ws layout (~29.6 MB @ N=1e5, E=3.2e6; fits <32MB budget)
    int* flag   = (int*)d_ws;              // 64
    int* bcnt   = flag + 64;               // 1024
    int* bstart = bcnt + 1024;             // 1025 (padded 1088)
    int* bcur   = bstart + 1088;           // 1024
    int* cnt    = bcur + 1024;             // N
    int* rp     = cnt + N;                 // N
    int* ss     = rp + N;                  // E  (phase-A buf aliases this)
    float* als  = (float*)(ss + E);        // N*2 (node-major [N][2])
    float* ald  = als + (long)N * 2;       // N*2 (node-major [N][2])
    unsigned* A = (unsigned*)(ald + (long)N * 2); // N*16 u32
    unsigned* h = A + (long)N * 16;               // N*16 u32
    float4* xp  = (float4*)(h + (long)N * 16);    // N float4 (16B rows)
    float* cvec = (float*)(xp + (long)N);         // 12 floats

    const int B = 256;
    auto cdiv = [](long a, long b) { return (int)((a + b - 1) / b); };
    const int NBKT = cdiv(N, 256);   // 256-node buckets (R12)

    // persistent grids: 2048 blocks x 4 waves (grid-stride over nodes)
    const int aggBlocks = 2048;

    // ---- two-level CSR build (dst-sorted), once, reused by all 3 layers
    prep<<<1, 1024, 0, stream>>>((const unsigned*)x, flag, bcnt);
    xprep<<<cdiv(N, B), B, 0, stream>>>(x, flag, W1, as1, ad1, xp, cvec, N);
    bhist<<<256, B, 0, stream>>>(ei1, E, bcnt);
    bscan<<<1, 1024, 0, stream>>>(bcnt, bstart, bcur);
    block_scatter<<<cdiv(E, CS_CHUNK), 512, 0, stream>>>(ei0, ei1, E, bcur, ss);
    fine_scatter<<<NBKT, B, 0, stream>>>(bstart, ss, ss, rp, cnt, N);

    // ---- Layer 1: 3 -> 2x16, commuted form: gather x (16B) only
    aggregate_l1<<<aggBlocks, B, 0, stream>>>(
        rp, cnt, ss, xp, cvec, W1, b1, flag, A, N);

    // ---- Layer 2: 32 -> 2x16 (R5 geometry: NCH=4/UNR=6, + gates)
    node_transform<1, 32, 2, 16><<<cdiv(N, B), B, 0, stream>>>(
        A, flag, W2, as2, ad2, h, als, ald, N);
    aggregate<2, 16, 4, 6, 0><<<aggBlocks, B, 0, stream>>>(
        rp, cnt, ss, h, als, ald, b2, nullptr, nullptr, flag, A, N);

    // ---- Layer 3: 32 -> 1x8, fused output head (+ gates)
    node_transform<1, 32, 1, 8><<<cdiv(N, B), B, 0, stream>>>(
        A, flag, W3, as3, ad3, h, als, ald, N);
    aggregate<1, 8, 2, 3, 1><<<aggBlocks, B, 0, stream>>>(
        rp, cnt, ss, h, als, ald, b3, Wo, bo, flag, d_out, N);
}

// Round 8
// 319.992 us; speedup vs baseline: 1.0485x; 1.0485x over previous
//
#include <hip/hip_runtime.h>
#include <hip/hip_bf16.h>
#include <math.h>

#define DEVINL __device__ __forceinline__

// Runtime-dtype load for EXTERNAL tensors: bf=1 -> bf16, bf=0 -> f32.
DEVINL float loadIn(const void* p, long i, int bf) {
    return bf ? __bfloat162float(((const __hip_bfloat16*)p)[i])
              : ((const float*)p)[i];
}

DEVINL float leaky(float v) { return fmaxf(v, 0.2f * v); }  // branch-free

DEVINL unsigned pack_bf16(float a, float b) {
    __hip_bfloat16 x = __float2bfloat16(a), y = __float2bfloat16(b);
    unsigned short ux = *reinterpret_cast<unsigned short*>(&x);
    unsigned short uy = *reinterpret_cast<unsigned short*>(&y);
    return (unsigned)ux | ((unsigned)uy << 16);
}
DEVINL float lo16(unsigned u) { return __uint_as_float(u << 16); }
DEVINL float hi16(unsigned u) { return __uint_as_float(u & 0xFFFF0000u); }

// ---------------------------------------------------------------------------
// prep: fused dtype sniffer (proven R2-R12) + bcnt zeroing. One block.
// ---------------------------------------------------------------------------
__global__ __launch_bounds__(1024) void prep(const unsigned* __restrict__ x,
                                             int* __restrict__ flag,
                                             int* __restrict__ bcnt) {
    __shared__ int sh[1024];
    int t = threadIdx.x;
    bcnt[t] = 0;
    int cnt = 0;
    for (int i = t; i < 2048; i += 1024) {
        unsigned ex = (x[i] >> 7) & 0xFFu;
        if (ex >= 110u && ex <= 140u) cnt++;
    }
    sh[t] = cnt;
    __syncthreads();
    for (int s = 512; s > 0; s >>= 1) {
        if (t < s) sh[t] += sh[t + s];
        __syncthreads();
    }
    if (t == 0) *flag = (sh[0] >= 1200) ? 1 : 0;
}

// ---------------------------------------------------------------------------
// Two-level CSR build. Bucket = dst >> 8 (256 nodes/bucket — R12 proven).
// ---------------------------------------------------------------------------
__global__ __launch_bounds__(256) void bhist(const int* __restrict__ dst, int E,
                                             int* __restrict__ bcnt) {
    __shared__ int lh[512];
    for (int i = threadIdx.x; i < 512; i += 256) lh[i] = 0;
    __syncthreads();
    int stride = gridDim.x * 256;
    for (int e = blockIdx.x * 256 + threadIdx.x; e < E; e += stride)
        atomicAdd(&lh[dst[e] >> 8], 1);
    __syncthreads();
    for (int i = threadIdx.x; i < 512; i += 256)
        if (lh[i]) atomicAdd(&bcnt[i], lh[i]);
}

__global__ __launch_bounds__(1024) void bscan(const int* __restrict__ bcnt,
                                              int* __restrict__ bstart,
                                              int* __restrict__ bcur) {
    __shared__ int sA[1024], sB[1024];
    int t = threadIdx.x;
    int c = bcnt[t];
    sA[t] = c;
    __syncthreads();
    int* a = sA; int* b = sB;
    for (int off = 1; off < 1024; off <<= 1) {
        int v = a[t] + ((t >= off) ? a[t - off] : 0);
        __syncthreads();
        b[t] = v;
        __syncthreads();
        int* tp = a; a = b; b = tp;
    }
    int excl = a[t] - c;
    bstart[t] = excl;
    bcur[t] = excl;
    if (t == 1023) bstart[1024] = a[t];
}

// Block-aggregated reservation scatter (R13 proven).
#define CS_CHUNK 16384
__global__ __launch_bounds__(512) void block_scatter(
    const int* __restrict__ srcIdx, const int* __restrict__ dstIdx, int E,
    int* __restrict__ bcur, int* __restrict__ buf) {
    __shared__ int lh[512];
    __shared__ int lcur[512];
    int t = threadIdx.x;
    int e0 = blockIdx.x * CS_CHUNK;
    int e1 = e0 + CS_CHUNK; if (e1 > E) e1 = E;

    if (t < 512) lh[t] = 0;
    __syncthreads();
    for (int e = e0 + t; e < e1; e += 512)
        atomicAdd(&lh[dstIdx[e] >> 8], 1);
    __syncthreads();
    if (t < 512) {
        int c = lh[t];
        lcur[t] = c ? atomicAdd(&bcur[t], c) : 0;
    }
    __syncthreads();
    for (int e = e0 + t; e < e1; e += 512) {
        int d = dstIdx[e];
        int s = srcIdx[e];
        int pos = atomicAdd(&lcur[d >> 8], 1);
        buf[pos] = ((d & 255) << 17) | s;   // src < 2^17 (N=1e5)
    }
}

// fine_scatter (R12 proven): one block per 256-node bucket.
#define FS_CAP 10240
__global__ __launch_bounds__(256) void fine_scatter(
    const int* __restrict__ bstart, int* buf, int* ss,
    int* __restrict__ rp, int* __restrict__ cnt, int N) {
    __shared__ int stage[FS_CAP];
    __shared__ int hcnt[256];
    __shared__ int hA[256], hB[256];
    __shared__ int lcur[256];
    int bkt = blockIdx.x;
    int t = threadIdx.x;
    int s0 = bstart[bkt];
    int m = bstart[bkt + 1] - s0;
    if (m > FS_CAP) m = FS_CAP;

    for (int i = t; i < m; i += 256) stage[i] = buf[s0 + i];
    hcnt[t] = 0;
    __syncthreads();
    for (int i = t; i < m; i += 256) atomicAdd(&hcnt[stage[i] >> 17], 1);
    __syncthreads();
    hA[t] = hcnt[t];
    __syncthreads();
    int* a = hA; int* b = hB;
    for (int off = 1; off < 256; off <<= 1) {
        int v = a[t] + ((t >= off) ? a[t - off] : 0);
        __syncthreads();
        b[t] = v;
        __syncthreads();
        int* tp = a; a = b; b = tp;
    }
    {
        int excl = a[t] - hcnt[t];
        lcur[t] = s0 + excl;
        int node = bkt * 256 + t;
        if (node < N) {
            rp[node] = s0 + excl;
            cnt[node] = hcnt[t];
        }
    }
    __syncthreads();
    for (int i = t; i < m; i += 256) {
        int v = stage[i];
        int pos = atomicAdd(&lcur[v >> 17], 1);
        ss[pos] = v & 0x1FFFF;
    }
}

// ---------------------------------------------------------------------------
// xprep (R17 proven): pad x -> xp[N][4] f32 + commuted attention vectors.
// ---------------------------------------------------------------------------
__global__ __launch_bounds__(256) void xprep(
    const void* __restrict__ x, const int* __restrict__ flagp,
    const void* __restrict__ W1, const void* __restrict__ as1,
    const void* __restrict__ ad1,
    float4* __restrict__ xp, float* __restrict__ cvec, int N)
{
    const int bf = *flagp;
    int n = blockIdx.x * 256 + threadIdx.x;
    if (n < N) {
        float4 v;
        v.x = loadIn(x, (long)n * 3 + 0, bf);
        v.y = loadIn(x, (long)n * 3 + 1, bf);
        v.z = loadIn(x, (long)n * 3 + 2, bf);
        v.w = 0.0f;
        xp[n] = v;
    }
    if (blockIdx.x == 0 && threadIdx.x < 12) {
        int t = threadIdx.x;
        int isd = t >= 6;
        int h = (t - 6 * isd) / 3;
        int k = (t - 6 * isd) % 3;
        const void* av = isd ? ad1 : as1;
        float s = 0.0f;
        for (int c = 0; c < 16; c++)
            s += loadIn(W1, k * 32 + h * 16 + c, bf) * loadIn(av, h * 16 + c, bf);
        cvec[t] = s;
    }
}

// ---------------------------------------------------------------------------
// aggregate_l1 (R17 proven): commuted layer-1 GAT, 16B/edge gather.
// ---------------------------------------------------------------------------
__global__ __launch_bounds__(256) void aggregate_l1(
    const int* __restrict__ rp_start, const int* __restrict__ cnt,
    const int* __restrict__ ss, const float4* __restrict__ xp,
    const float* __restrict__ cvec,
    const void* __restrict__ W1, const void* __restrict__ b1,
    const int* __restrict__ flagp,
    unsigned* __restrict__ xout, int N)
{
    const int bf = *flagp;
    __shared__ float Wl[96];
    __shared__ float bl[32];
    for (int i = threadIdx.x; i < 96; i += 256) Wl[i] = loadIn(W1, i, bf);
    for (int i = threadIdx.x; i < 32; i += 256) bl[i] = loadIn(b1, i, bf);
    __syncthreads();

    int lane = threadIdx.x & 63;
    int g = lane >> 4;
    int q = lane & 15;
    int wid = threadIdx.x >> 6;

    float cs[2][3], cd[2][3];
#pragma unroll
    for (int h = 0; h < 2; h++)
#pragma unroll
        for (int k = 0; k < 3; k++) {
            cs[h][k] = cvec[h * 3 + k];
            cd[h][k] = cvec[6 + h * 3 + k];
        }

    const int nstride = gridDim.x * 16;
    for (int node = blockIdx.x * 16 + wid * 4 + g; ; node += nstride) {
        if (node - g >= N) break;
        bool valid = node < N;
        int idx = valid ? node : 0;
        int start = rp_start[idx];
        int deg = valid ? cnt[idx] : 0;
        float4 xn = xp[idx];

        float alsn[2], aldn[2];
#pragma unroll
        for (int h = 0; h < 2; h++) {
            alsn[h] = xn.x * cs[h][0] + xn.y * cs[h][1] + xn.z * cs[h][2];
            aldn[h] = xn.x * cd[h][0] + xn.y * cd[h][1] + xn.z * cd[h][2];
        }

        float a00 = 0.f, a01 = 0.f, a02 = 0.f, s0 = 0.f;
        float a10 = 0.f, a11 = 0.f, a12 = 0.f, s1 = 0.f;

        if (q == 0 && valid) {
            float e0 = __expf(fminf(leaky(alsn[0] + aldn[0]), 80.0f));
            float e1 = __expf(fminf(leaky(alsn[1] + aldn[1]), 80.0f));
            a00 = e0 * xn.x; a01 = e0 * xn.y; a02 = e0 * xn.z; s0 = e0;
            a10 = e1 * xn.x; a11 = e1 * xn.y; a12 = e1 * xn.z; s1 = e1;
        }

        for (int kb = q; kb < deg; kb += 32) {
            int k2 = kb + 16;
            bool ok2 = k2 < deg;
            int sA = ss[start + kb];
            int sB = ss[start + (ok2 ? k2 : kb)];
            float4 xa = xp[sA];
            float4 xb = xp[sB];
            {
                float l0 = xa.x * cs[0][0] + xa.y * cs[0][1] + xa.z * cs[0][2] + aldn[0];
                float l1 = xa.x * cs[1][0] + xa.y * cs[1][1] + xa.z * cs[1][2] + aldn[1];
                float e0 = __expf(fminf(leaky(l0), 80.0f));
                float e1 = __expf(fminf(leaky(l1), 80.0f));
                a00 = fmaf(xa.x, e0, a00); a01 = fmaf(xa.y, e0, a01);
                a02 = fmaf(xa.z, e0, a02); s0 += e0;
                a10 = fmaf(xa.x, e1, a10); a11 = fmaf(xa.y, e1, a11);
                a12 = fmaf(xa.z, e1, a12); s1 += e1;
            }
            {
                float l0 = xb.x * cs[0][0] + xb.y * cs[0][1] + xb.z * cs[0][2] + aldn[0];
                float l1 = xb.x * cs[1][0] + xb.y * cs[1][1] + xb.z * cs[1][2] + aldn[1];
                float e0 = ok2 ? __expf(fminf(leaky(l0), 80.0f)) : 0.0f;
                float e1 = ok2 ? __expf(fminf(leaky(l1), 80.0f)) : 0.0f;
                a00 = fmaf(xb.x, e0, a00); a01 = fmaf(xb.y, e0, a01);
                a02 = fmaf(xb.z, e0, a02); s0 += e0;
                a10 = fmaf(xb.x, e1, a10); a11 = fmaf(xb.y, e1, a11);
                a12 = fmaf(xb.z, e1, a12); s1 += e1;
            }
        }

#pragma unroll
        for (int off = 1; off < 16; off <<= 1) {
            a00 += __shfl_xor(a00, off, 64); a01 += __shfl_xor(a01, off, 64);
            a02 += __shfl_xor(a02, off, 64); s0  += __shfl_xor(s0,  off, 64);
            a10 += __shfl_xor(a10, off, 64); a11 += __shfl_xor(a11, off, 64);
            a12 += __shfl_xor(a12, off, 64); s1  += __shfl_xor(s1,  off, 64);
        }

        if (valid) {
            int h = q >> 3;
            float inv = 1.0f / ((h ? s1 : s0) + 1e-16f);
            float g0 = (h ? a10 : a00) * inv;
            float g1 = (h ? a11 : a01) * inv;
            float g2 = (h ? a12 : a02) * inv;
            int c0 = 2 * q;
            float v0 = g0 * Wl[c0]      + g1 * Wl[32 + c0]      + g2 * Wl[64 + c0]      + bl[c0];
            float v1 = g0 * Wl[c0 + 1]  + g1 * Wl[32 + c0 + 1]  + g2 * Wl[64 + c0 + 1]  + bl[c0 + 1];
            v0 = v0 > 0.0f ? v0 : __expf(fminf(v0, 0.0f)) - 1.0f;
            v1 = v1 > 0.0f ? v1 : __expf(fminf(v1, 0.0f)) - 1.0f;
            xout[(long)node * 16 + q] = pack_bf16(v0, v1);
        }
    }
}

// ---------------------------------------------------------------------------
// node_transform (R9/R1 proven, node-major). Layers 2-3 only.
// ---------------------------------------------------------------------------
template <int XMODE, int C_IN, int H, int C>
__global__ __launch_bounds__(256) void node_transform(
    const void* __restrict__ xin, const int* __restrict__ flagp,
    const void* __restrict__ W, const void* __restrict__ a_s,
    const void* __restrict__ a_d,
    unsigned* __restrict__ h2, float* __restrict__ als,
    float* __restrict__ ald, int N)
{
    const int bf = *flagp;
    constexpr int HC = H * C;
    __shared__ float Ws[C_IN * HC];
    __shared__ float asS[HC];
    __shared__ float adS[HC];
    for (int i = threadIdx.x; i < C_IN * HC; i += 256) Ws[i] = loadIn(W, i, bf);
    for (int i = threadIdx.x; i < HC; i += 256) {
        asS[i] = loadIn(a_s, i, bf);
        adS[i] = loadIn(a_d, i, bf);
    }
    __syncthreads();

    int n = blockIdx.x * 256 + threadIdx.x;
    if (n >= N) return;

    float xv[C_IN];
    if (XMODE) {
        const uint4* x4 = (const uint4*)xin;
#pragma unroll
        for (int q = 0; q < C_IN / 8; q++) {
            uint4 w = x4[(long)n * (C_IN / 8) + q];
            xv[q * 8 + 0] = lo16(w.x); xv[q * 8 + 1] = hi16(w.x);
            xv[q * 8 + 2] = lo16(w.y); xv[q * 8 + 3] = hi16(w.y);
            xv[q * 8 + 4] = lo16(w.z); xv[q * 8 + 5] = hi16(w.z);
            xv[q * 8 + 6] = lo16(w.w); xv[q * 8 + 7] = hi16(w.w);
        }
    } else {
#pragma unroll
        for (int k = 0; k < C_IN; k++) xv[k] = loadIn(xin, (long)n * C_IN + k, bf);
    }

    float hv[HC];
#pragma unroll
    for (int j = 0; j < HC; j++) {
        float v = 0.0f;
#pragma unroll
        for (int k = 0; k < C_IN; k++) v = fmaf(xv[k], Ws[k * HC + j], v);
        hv[j] = v;
    }
#pragma unroll
    for (int jj = 0; jj < HC / 2; jj++)
        h2[(long)n * (HC / 2) + jj] = pack_bf16(hv[2 * jj], hv[2 * jj + 1]);

#pragma unroll
    for (int hh = 0; hh < H; hh++) {
        float vs = 0.0f, vd = 0.0f;
#pragma unroll
        for (int c = 0; c < C; c++) {
            vs = fmaf(hv[hh * C + c], asS[hh * C + c], vs);
            vd = fmaf(hv[hh * C + c], adS[hh * C + c], vd);
        }
        als[(long)n * H + hh] = vs;
        ald[(long)n * H + hh] = vd;
    }
}

// ---------------------------------------------------------------------------
// aggregate (R21 = R18/R5 body, 3-DEEP pipeline): R6 proved in-flight loads
// are the binding asset; R7 proved load/use batches must stay branch-free
// (gates fragmented vmcnt waits -> 80us). R5's 2-deep gives each gather ~1
// body (~350-400cyc) of slack, but h2 misses per-XCD L2 (6.4MB > 4MB) ->
// ~600cyc latency: the residual 27% stall. 3-deep issues slot C's gathers
// TWO bodies before use (~700-800cyc slack > latency), branch-free, same
// instruction count. Cost: 3rd slot's registers (~5-6 waves/SIMD instead of
// 8) — acceptable because per-wave stall, not wave count, binds.
// Schedule, body computing slot A (B next, C after):
//   (a) AGG_ISSUE_G(C)      — SS(C) landed last body; used in 2 bodies
//   (b) AGG_LOADCSR(A,+3ns) — slot A reused 3 bodies ahead (s_load-ish)
//   (c) compute A           — G(A) issued 2 bodies ago: fully landed
//   (e) AGG_ISSUE_SS(A)     — CSR(A) landed during compute
//   (d) finish A            — butterfly, epilogue, store
// ---------------------------------------------------------------------------
template <int H, int C, int NCH, int UNR, int FUSE>
__global__ __launch_bounds__(256) void aggregate(
    const int* __restrict__ rp_start, const int* __restrict__ cnt,
    const int* __restrict__ ss,
    const unsigned* __restrict__ h2,
    const float* __restrict__ als, const float* __restrict__ ald,
    const void* __restrict__ bias, const void* __restrict__ Wo,
    const void* __restrict__ bo, const int* __restrict__ flagp,
    void* __restrict__ xout, int N)
{
    constexpr int HC = H * C;
    constexpr int J = HC / NCH;     // lanes per edge row
    constexpr int EPW = 64 / J;     // edge rows per wave
    constexpr int SLOTS = UNR * EPW;
    const int bf = *flagp;
    int lane = threadIdx.x & 63;
    int p = lane / J;
    int j = lane % J;
    int c0 = NCH * j;
    int head = c0 / C;
    const float* __restrict__ alsH = als + head;

    float bv[NCH];
#pragma unroll
    for (int i = 0; i < NCH; i++) bv[i] = loadIn(bias, c0 + i, bf);
    float wov[NCH];
    float bov = 0.0f;
    if constexpr (FUSE) {
#pragma unroll
        for (int i = 0; i < NCH; i++) wov[i] = loadIn(Wo, c0 + i, bf);
        bov = loadIn(bo, 0, bf);
    }

    const int nstride = gridDim.x << 2;   // 4 waves per block
    const int node0 = (blockIdx.x << 2) + (threadIdx.x >> 6);
    if (node0 >= N) return;

    // ---- pipeline state: 3 slots, all statically indexed (rule #20)
    int nd0, nd1, nd2, st0, st1, st2, dg0, dg1, dg2;
    float an0, an1, an2, sa0, sa1, sa2;
    uint2 sq0, sq1, sq2; unsigned sw0, sw1, sw2;   // self h row fragments
    int sr0[UNR], sr1[UNR], sr2[UNR];
    float av0[UNR], av1[UNR], av2[UNR];
    uint2 hq0[UNR], hq1[UNR], hq2[UNR];
    unsigned hw0[UNR], hw1[UNR], hw2[UNR];

#define AGG_LOADCSR(S, NODE) {                                              \
    int nn_ = (NODE); nd##S = nn_;                                          \
    int ii_ = nn_ < N ? nn_ : N - 1;                                        \
    st##S = rp_start[ii_];                                                  \
    dg##S = nn_ < N ? cnt[ii_] : 0;                                         \
    an##S = ald[ii_ * H + head];                                            \
    sa##S = alsH[ii_ * H];                                                  \
    if constexpr (NCH == 4) sq##S = ((const uint2*)h2)[ii_ * (HC / 4) + j]; \
    else sw##S = h2[ii_ * (HC / 2) + j]; }

#define AGG_ISSUE_SS(S) {                                                   \
    int dm1_ = dg##S > 0 ? dg##S - 1 : 0;                                   \
    _Pragma("unroll") for (int u = 0; u < UNR; u++) {                       \
        int k_ = p + u * EPW;                                               \
        sr##S[u] = ss[st##S + (k_ < dg##S ? k_ : dm1_)]; } }

#define AGG_ISSUE_G(S) {                                                    \
    _Pragma("unroll") for (int u = 0; u < UNR; u++) {                       \
        av##S[u] = alsH[sr##S[u] * H];                                      \
        if constexpr (NCH == 4)                                             \
            hq##S[u] = ((const uint2*)h2)[sr##S[u] * (HC / 4) + j];         \
        else hw##S[u] = h2[sr##S[u] * (HC / 2) + j]; } }

#define AGG_BODY3(A, B, Cx) {                                               \
    int node_c = nd##A, start_c = st##A, deg_c = dg##A;                     \
    float an_c = an##A, sa_c = sa##A;                                       \
    uint2 sq_c = sq##A; unsigned sw_c = sw##A; (void)sq_c; (void)sw_c;      \
    /* (a) issue gathers for slot Cx (used 2 bodies from now) */            \
    AGG_ISSUE_G(Cx);                                                        \
    /* (b) prefetch CSR+self for node_c + 3*nstride into slot A */          \
    AGG_LOADCSR(A, node_c + 3 * nstride);                                   \
    /* (c) compute CUR (G(A) issued 2 bodies ago — fully landed) */         \
    float acc[NCH]; float ssum = 0.0f;                                      \
    _Pragma("unroll") for (int i = 0; i < NCH; i++) acc[i] = 0.0f;          \
    if (p == 0) {                                                           \
        float es_ = __expf(fminf(leaky(sa_c + an_c), 80.0f));               \
        if constexpr (NCH == 4) {                                           \
            acc[0] = lo16(sq_c.x) * es_; acc[1] = hi16(sq_c.x) * es_;       \
            acc[2] = lo16(sq_c.y) * es_; acc[3] = hi16(sq_c.y) * es_;       \
        } else {                                                            \
            acc[0] = lo16(sw_c) * es_; acc[1] = hi16(sw_c) * es_;           \
        }                                                                   \
        ssum = es_;                                                         \
    }                                                                       \
    _Pragma("unroll") for (int u = 0; u < UNR; u++) {                       \
        int k_ = p + u * EPW;                                               \
        float e_ = (k_ < deg_c)                                             \
            ? __expf(fminf(leaky(av##A[u] + an_c), 80.0f)) : 0.0f;          \
        if constexpr (NCH == 4) {                                           \
            acc[0] = fmaf(lo16(hq##A[u].x), e_, acc[0]);                    \
            acc[1] = fmaf(hi16(hq##A[u].x), e_, acc[1]);                    \
            acc[2] = fmaf(lo16(hq##A[u].y), e_, acc[2]);                    \
            acc[3] = fmaf(hi16(hq##A[u].y), e_, acc[3]);                    \
        } else {                                                            \
            acc[0] = fmaf(lo16(hw##A[u]), e_, acc[0]);                      \
            acc[1] = fmaf(hi16(hw##A[u]), e_, acc[1]);                      \
        }                                                                   \
        ssum += e_;                                                         \
    }                                                                       \
    /* rare tail: deg > SLOTS (wave-uniform branch) */                      \
    if (deg_c > SLOTS) {                                                    \
        for (int kb_ = SLOTS + p; kb_ < deg_c; kb_ += EPW) {                \
            int s_ = ss[start_c + kb_];                                     \
            float e_ = __expf(fminf(leaky(alsH[s_ * H] + an_c), 80.0f));    \
            if constexpr (NCH == 4) {                                       \
                uint2 hv_ = ((const uint2*)h2)[s_ * (HC / 4) + j];          \
                acc[0] = fmaf(lo16(hv_.x), e_, acc[0]);                     \
                acc[1] = fmaf(hi16(hv_.x), e_, acc[1]);                     \
                acc[2] = fmaf(lo16(hv_.y), e_, acc[2]);                     \
                acc[3] = fmaf(hi16(hv_.y), e_, acc[3]);                     \
            } else {                                                        \
                unsigned hv_ = h2[s_ * (HC / 2) + j];                       \
                acc[0] = fmaf(lo16(hv_), e_, acc[0]);                       \
                acc[1] = fmaf(hi16(hv_), e_, acc[1]);                       \
            }                                                               \
            ssum += e_;                                                     \
        }                                                                   \
    }                                                                       \
    /* (e) issue ss for slot A's new node (CSR landed during compute) */    \
    AGG_ISSUE_SS(A);                                                        \
    /* (d) finish CUR */                                                    \
    _Pragma("unroll") for (int off = J; off < 64; off <<= 1) {              \
        _Pragma("unroll") for (int i = 0; i < NCH; i++)                     \
            acc[i] += __shfl_xor(acc[i], off, 64);                          \
        ssum += __shfl_xor(ssum, off, 64);                                  \
    }                                                                       \
    float inv = 1.0f / (ssum + 1e-16f);                                     \
    float v[NCH];                                                           \
    _Pragma("unroll") for (int i = 0; i < NCH; i++) {                       \
        float t_ = acc[i] * inv + bv[i];                                    \
        v[i] = t_ > 0.0f ? t_ : __expf(fminf(t_, 0.0f)) - 1.0f;             \
    }                                                                       \
    if constexpr (FUSE) {                                                   \
        float r_ = 0.0f;                                                    \
        _Pragma("unroll") for (int i = 0; i < NCH; i++)                     \
            r_ = fmaf(v[i], wov[i], r_);                                    \
        _Pragma("unroll") for (int off = 1; off < J; off <<= 1)             \
            r_ += __shfl_xor(r_, off, 64);                                  \
        if (lane == 0 && node_c < N) {                                      \
            r_ += bov;                                                      \
            if (bf) ((__hip_bfloat16*)xout)[node_c] = __float2bfloat16(r_); \
            else    ((float*)xout)[node_c] = r_;                            \
        }                                                                   \
    } else {                                                                \
        if (p == 0 && node_c < N) {                                         \
            if constexpr (NCH == 4) {                                       \
                uint2 o_; o_.x = pack_bf16(v[0], v[1]);                     \
                o_.y = pack_bf16(v[2], v[3]);                               \
                ((uint2*)xout)[node_c * (HC / 4) + j] = o_;                 \
            } else {                                                        \
                ((unsigned*)xout)[node_c * (HC / 2) + j] =                  \
                    pack_bf16(v[0], v[1]);                                  \
            }                                                               \
        }                                                                   \
    } }

    // ---- prologue: CSR for slots 0..2; ss for all; gathers for 0 and 1
    AGG_LOADCSR(0, node0);
    AGG_LOADCSR(1, node0 + nstride);
    AGG_LOADCSR(2, node0 + 2 * nstride);
    AGG_ISSUE_SS(0);
    AGG_ISSUE_SS(1);
    AGG_ISSUE_SS(2);
    AGG_ISSUE_G(0);
    AGG_ISSUE_G(1);

    for (;;) {
        AGG_BODY3(0, 1, 2);
        if (nd1 >= N) break;
        AGG_BODY3(1, 2, 0);
        if (nd2 >= N) break;
        AGG_BODY3(2, 0, 1);
        if (nd0 >= N) break;
    }

#undef AGG_LOADCSR
#undef AGG_ISSUE_SS
#undef AGG_ISSUE_G
#undef AGG_BODY3
}

// ---------------------------------------------------------------------------
extern "C" void kernel_launch(void* const* d_in, const int* in_sizes, int n_in,
                              void* d_out, int out_size, void* d_ws, size_t ws_size,
                              hipStream_t stream) {
    const void* x   = d_in[0];
    const int*  ei  = (const int*)d_in[1];
    const void* W1  = d_in[2];
    const void* as1 = d_in[3];
    const void* ad1 = d_in[4];
    const void* b1  = d_in[5];
    const void* W2  = d_in[6];
    const void* as2 = d_in[7];
    const void* ad2 = d_in[8];
    const void* b2  = d_in[9];
    const void* W3  = d_in[10];
    const void* as3 = d_in[11];
    const void* ad3 = d_in[12];
    const void* b3  = d_in[13];
    const void* Wo  = d_in[14];
    const void* bo  = d_in[15];

    const int N = in_sizes[0] / 3;
    const int E = in_sizes[1] / 2;
    const int* ei0 = ei;       // src
    const int* ei1 = ei + E;   // dst

    // ---- ws layout (~29.6 MB @ N=1e5, E=3.2e6; fits <32MB budget)
    int* flag   = (int*)d_ws;              // 64
    int* bcnt   = flag + 64;               // 1024
    int* bstart = bcnt + 1024;             // 1025 (padded 1088)
    int* bcur   = bstart + 1088;           // 1024
    int* cnt    = bcur + 1024;             // N
    int* rp     = cnt + N;                 // N
    int* ss     = rp + N;                  // E  (phase-A buf aliases this)
    float* als  = (float*)(ss + E);        // N*2 (node-major [N][2])
    float* ald  = als + (long)N * 2;       // N*2 (node-major [N][2])
    unsigned* A = (unsigned*)(ald + (long)N * 2); // N*16 u32
    unsigned* h = A + (long)N * 16;               // N*16 u32
    float4* xp  = (float4*)(h + (long)N * 16);    // N float4 (16B rows)
    float* cvec = (float*)(xp + (long)N);         // 12 floats

    const int B = 256;
    auto cdiv = [](long a, long b) { return (int)((a + b - 1) / b); };
    const int NBKT = cdiv(N, 256);   // 256-node buckets (R12)

    // persistent grids: 2048 blocks x 4 waves (grid-stride over nodes)
    const int aggBlocks = 2048;

    // ---- two-level CSR build (dst-sorted), once, reused by all 3 layers
    prep<<<1, 1024, 0, stream>>>((const unsigned*)x, flag, bcnt);
    xprep<<<cdiv(N, B), B, 0, stream>>>(x, flag, W1, as1, ad1, xp, cvec, N);
    bhist<<<256, B, 0, stream>>>(ei1, E, bcnt);
    bscan<<<1, 1024, 0, stream>>>(bcnt, bstart, bcur);
    block_scatter<<<cdiv(E, CS_CHUNK), 512, 0, stream>>>(ei0, ei1, E, bcur, ss);
    fine_scatter<<<NBKT, B, 0, stream>>>(bstart, ss, ss, rp, cnt, N);

    // ---- Layer 1: 3 -> 2x16, commuted form: gather x (16B) only
    aggregate_l1<<<aggBlocks, B, 0, stream>>>(
        rp, cnt, ss, xp, cvec, W1, b1, flag, A, N);

    // ---- Layer 2: 32 -> 2x16 (3-deep pipelined aggregate)
    node_transform<1, 32, 2, 16><<<cdiv(N, B), B, 0, stream>>>(
        A, flag, W2, as2, ad2, h, als, ald, N);
    aggregate<2, 16, 4, 6, 0><<<aggBlocks, B, 0, stream>>>(
        rp, cnt, ss, h, als, ald, b2, nullptr, nullptr, flag, A, N);

    // ---- Layer 3: 32 -> 1x8, fused output head (3-deep pipelined)
    node_transform<1, 32, 1, 8><<<cdiv(N, B), B, 0, stream>>>(
        A, flag, W3, as3, ad3, h, als, ald, N);
    aggregate<1, 8, 2, 3, 1><<<aggBlocks, B, 0, stream>>>(
        rp, cnt, ss, h, als, ald, b3, Wo, bo, flag, d_out, N);
}

// Round 10
// 314.484 us; speedup vs baseline: 1.0669x; 1.0175x over previous
//
#include <hip/hip_runtime.h>
#include <hip/hip_bf16.h>
#include <math.h>

#define DEVINL __device__ __forceinline__

// Runtime-dtype load for EXTERNAL tensors: bf=1 -> bf16, bf=0 -> f32.
DEVINL float loadIn(const void* p, long i, int bf) {
    return bf ? __bfloat162float(((const __hip_bfloat16*)p)[i])
              : ((const float*)p)[i];
}

DEVINL float leaky(float v) { return fmaxf(v, 0.2f * v); }  // branch-free

DEVINL unsigned pack_bf16(float a, float b) {
    __hip_bfloat16 x = __float2bfloat16(a), y = __float2bfloat16(b);
    unsigned short ux = *reinterpret_cast<unsigned short*>(&x);
    unsigned short uy = *reinterpret_cast<unsigned short*>(&y);
    return (unsigned)ux | ((unsigned)uy << 16);
}
DEVINL float lo16(unsigned u) { return __uint_as_float(u << 16); }
DEVINL float hi16(unsigned u) { return __uint_as_float(u & 0xFFFF0000u); }

// ---------------------------------------------------------------------------
// prep: fused dtype sniffer (proven R2-R12) + bcnt zeroing. One block.
// ---------------------------------------------------------------------------
__global__ __launch_bounds__(1024) void prep(const unsigned* __restrict__ x,
                                             int* __restrict__ flag,
                                             int* __restrict__ bcnt) {
    __shared__ int sh[1024];
    int t = threadIdx.x;
    bcnt[t] = 0;
    int cnt = 0;
    for (int i = t; i < 2048; i += 1024) {
        unsigned ex = (x[i] >> 7) & 0xFFu;
        if (ex >= 110u && ex <= 140u) cnt++;
    }
    sh[t] = cnt;
    __syncthreads();
    for (int s = 512; s > 0; s >>= 1) {
        if (t < s) sh[t] += sh[t + s];
        __syncthreads();
    }
    if (t == 0) *flag = (sh[0] >= 1200) ? 1 : 0;
}

// ---------------------------------------------------------------------------
// Two-level CSR build. Bucket = dst >> 8 (256 nodes/bucket — R12 proven).
// ---------------------------------------------------------------------------
__global__ __launch_bounds__(256) void bhist(const int* __restrict__ dst, int E,
                                             int* __restrict__ bcnt) {
    __shared__ int lh[512];
    for (int i = threadIdx.x; i < 512; i += 256) lh[i] = 0;
    __syncthreads();
    int stride = gridDim.x * 256;
    for (int e = blockIdx.x * 256 + threadIdx.x; e < E; e += stride)
        atomicAdd(&lh[dst[e] >> 8], 1);
    __syncthreads();
    for (int i = threadIdx.x; i < 512; i += 256)
        if (lh[i]) atomicAdd(&bcnt[i], lh[i]);
}

__global__ __launch_bounds__(1024) void bscan(const int* __restrict__ bcnt,
                                              int* __restrict__ bstart,
                                              int* __restrict__ bcur) {
    __shared__ int sA[1024], sB[1024];
    int t = threadIdx.x;
    int c = bcnt[t];
    sA[t] = c;
    __syncthreads();
    int* a = sA; int* b = sB;
    for (int off = 1; off < 1024; off <<= 1) {
        int v = a[t] + ((t >= off) ? a[t - off] : 0);
        __syncthreads();
        b[t] = v;
        __syncthreads();
        int* tp = a; a = b; b = tp;
    }
    int excl = a[t] - c;
    bstart[t] = excl;
    bcur[t] = excl;
    if (t == 1023) bstart[1024] = a[t];
}

// Block-aggregated reservation scatter (R13 proven).
#define CS_CHUNK 16384
__global__ __launch_bounds__(512) void block_scatter(
    const int* __restrict__ srcIdx, const int* __restrict__ dstIdx, int E,
    int* __restrict__ bcur, int* __restrict__ buf) {
    __shared__ int lh[512];
    __shared__ int lcur[512];
    int t = threadIdx.x;
    int e0 = blockIdx.x * CS_CHUNK;
    int e1 = e0 + CS_CHUNK; if (e1 > E) e1 = E;

    if (t < 512) lh[t] = 0;
    __syncthreads();
    for (int e = e0 + t; e < e1; e += 512)
        atomicAdd(&lh[dstIdx[e] >> 8], 1);
    __syncthreads();
    if (t < 512) {
        int c = lh[t];
        lcur[t] = c ? atomicAdd(&bcur[t], c) : 0;
    }
    __syncthreads();
    for (int e = e0 + t; e < e1; e += 512) {
        int d = dstIdx[e];
        int s = srcIdx[e];
        int pos = atomicAdd(&lcur[d >> 8], 1);
        buf[pos] = ((d & 255) << 17) | s;   // src < 2^17 (N=1e5)
    }
}

// fine_scatter (R12 proven): one block per 256-node bucket.
#define FS_CAP 10240
__global__ __launch_bounds__(256) void fine_scatter(
    const int* __restrict__ bstart, int* buf, int* ss,
    int* __restrict__ rp, int* __restrict__ cnt, int N) {
    __shared__ int stage[FS_CAP];
    __shared__ int hcnt[256];
    __shared__ int hA[256], hB[256];
    __shared__ int lcur[256];
    int bkt = blockIdx.x;
    int t = threadIdx.x;
    int s0 = bstart[bkt];
    int m = bstart[bkt + 1] - s0;
    if (m > FS_CAP) m = FS_CAP;

    for (int i = t; i < m; i += 256) stage[i] = buf[s0 + i];
    hcnt[t] = 0;
    __syncthreads();
    for (int i = t; i < m; i += 256) atomicAdd(&hcnt[stage[i] >> 17], 1);
    __syncthreads();
    hA[t] = hcnt[t];
    __syncthreads();
    int* a = hA; int* b = hB;
    for (int off = 1; off < 256; off <<= 1) {
        int v = a[t] + ((t >= off) ? a[t - off] : 0);
        __syncthreads();
        b[t] = v;
        __syncthreads();
        int* tp = a; a = b; b = tp;
    }
    {
        int excl = a[t] - hcnt[t];
        lcur[t] = s0 + excl;
        int node = bkt * 256 + t;
        if (node < N) {
            rp[node] = s0 + excl;
            cnt[node] = hcnt[t];
        }
    }
    __syncthreads();
    for (int i = t; i < m; i += 256) {
        int v = stage[i];
        int pos = atomicAdd(&lcur[v >> 17], 1);
        ss[pos] = v & 0x1FFFF;
    }
}

// ---------------------------------------------------------------------------
// xprep (R17 proven): pad x -> xp[N][4] f32 + commuted attention vectors.
// ---------------------------------------------------------------------------
__global__ __launch_bounds__(256) void xprep(
    const void* __restrict__ x, const int* __restrict__ flagp,
    const void* __restrict__ W1, const void* __restrict__ as1,
    const void* __restrict__ ad1,
    float4* __restrict__ xp, float* __restrict__ cvec, int N)
{
    const int bf = *flagp;
    int n = blockIdx.x * 256 + threadIdx.x;
    if (n < N) {
        float4 v;
        v.x = loadIn(x, (long)n * 3 + 0, bf);
        v.y = loadIn(x, (long)n * 3 + 1, bf);
        v.z = loadIn(x, (long)n * 3 + 2, bf);
        v.w = 0.0f;
        xp[n] = v;
    }
    if (blockIdx.x == 0 && threadIdx.x < 12) {
        int t = threadIdx.x;
        int isd = t >= 6;
        int h = (t - 6 * isd) / 3;
        int k = (t - 6 * isd) % 3;
        const void* av = isd ? ad1 : as1;
        float s = 0.0f;
        for (int c = 0; c < 16; c++)
            s += loadIn(W1, k * 32 + h * 16 + c, bf) * loadIn(av, h * 16 + c, bf);
        cvec[t] = s;
    }
}

// ---------------------------------------------------------------------------
// aggregate_l1 (R17 proven): commuted layer-1 GAT, 16B/edge gather.
// ---------------------------------------------------------------------------
__global__ __launch_bounds__(256) void aggregate_l1(
    const int* __restrict__ rp_start, const int* __restrict__ cnt,
    const int* __restrict__ ss, const float4* __restrict__ xp,
    const float* __restrict__ cvec,
    const void* __restrict__ W1, const void* __restrict__ b1,
    const int* __restrict__ flagp,
    unsigned* __restrict__ xout, int N)
{
    const int bf = *flagp;
    __shared__ float Wl[96];
    __shared__ float bl[32];
    for (int i = threadIdx.x; i < 96; i += 256) Wl[i] = loadIn(W1, i, bf);
    for (int i = threadIdx.x; i < 32; i += 256) bl[i] = loadIn(b1, i, bf);
    __syncthreads();

    int lane = threadIdx.x & 63;
    int g = lane >> 4;
    int q = lane & 15;
    int wid = threadIdx.x >> 6;

    float cs[2][3], cd[2][3];
#pragma unroll
    for (int h = 0; h < 2; h++)
#pragma unroll
        for (int k = 0; k < 3; k++) {
            cs[h][k] = cvec[h * 3 + k];
            cd[h][k] = cvec[6 + h * 3 + k];
        }

    const int nstride = gridDim.x * 16;
    for (int node = blockIdx.x * 16 + wid * 4 + g; ; node += nstride) {
        if (node - g >= N) break;
        bool valid = node < N;
        int idx = valid ? node : 0;
        int start = rp_start[idx];
        int deg = valid ? cnt[idx] : 0;
        float4 xn = xp[idx];

        float alsn[2], aldn[2];
#pragma unroll
        for (int h = 0; h < 2; h++) {
            alsn[h] = xn.x * cs[h][0] + xn.y * cs[h][1] + xn.z * cs[h][2];
            aldn[h] = xn.x * cd[h][0] + xn.y * cd[h][1] + xn.z * cd[h][2];
        }

        float a00 = 0.f, a01 = 0.f, a02 = 0.f, s0 = 0.f;
        float a10 = 0.f, a11 = 0.f, a12 = 0.f, s1 = 0.f;

        if (q == 0 && valid) {
            float e0 = __expf(fminf(leaky(alsn[0] + aldn[0]), 80.0f));
            float e1 = __expf(fminf(leaky(alsn[1] + aldn[1]), 80.0f));
            a00 = e0 * xn.x; a01 = e0 * xn.y; a02 = e0 * xn.z; s0 = e0;
            a10 = e1 * xn.x; a11 = e1 * xn.y; a12 = e1 * xn.z; s1 = e1;
        }

        for (int kb = q; kb < deg; kb += 32) {
            int k2 = kb + 16;
            bool ok2 = k2 < deg;
            int sA = ss[start + kb];
            int sB = ss[start + (ok2 ? k2 : kb)];
            float4 xa = xp[sA];
            float4 xb = xp[sB];
            {
                float l0 = xa.x * cs[0][0] + xa.y * cs[0][1] + xa.z * cs[0][2] + aldn[0];
                float l1 = xa.x * cs[1][0] + xa.y * cs[1][1] + xa.z * cs[1][2] + aldn[1];
                float e0 = __expf(fminf(leaky(l0), 80.0f));
                float e1 = __expf(fminf(leaky(l1), 80.0f));
                a00 = fmaf(xa.x, e0, a00); a01 = fmaf(xa.y, e0, a01);
                a02 = fmaf(xa.z, e0, a02); s0 += e0;
                a10 = fmaf(xa.x, e1, a10); a11 = fmaf(xa.y, e1, a11);
                a12 = fmaf(xa.z, e1, a12); s1 += e1;
            }
            {
                float l0 = xb.x * cs[0][0] + xb.y * cs[0][1] + xb.z * cs[0][2] + aldn[0];
                float l1 = xb.x * cs[1][0] + xb.y * cs[1][1] + xb.z * cs[1][2] + aldn[1];
                float e0 = ok2 ? __expf(fminf(leaky(l0), 80.0f)) : 0.0f;
                float e1 = ok2 ? __expf(fminf(leaky(l1), 80.0f)) : 0.0f;
                a00 = fmaf(xb.x, e0, a00); a01 = fmaf(xb.y, e0, a01);
                a02 = fmaf(xb.z, e0, a02); s0 += e0;
                a10 = fmaf(xb.x, e1, a10); a11 = fmaf(xb.y, e1, a11);
                a12 = fmaf(xb.z, e1, a12); s1 += e1;
            }
        }

#pragma unroll
        for (int off = 1; off < 16; off <<= 1) {
            a00 += __shfl_xor(a00, off, 64); a01 += __shfl_xor(a01, off, 64);
            a02 += __shfl_xor(a02, off, 64); s0  += __shfl_xor(s0,  off, 64);
            a10 += __shfl_xor(a10, off, 64); a11 += __shfl_xor(a11, off, 64);
            a12 += __shfl_xor(a12, off, 64); s1  += __shfl_xor(s1,  off, 64);
        }

        if (valid) {
            int h = q >> 3;
            float inv = 1.0f / ((h ? s1 : s0) + 1e-16f);
            float g0 = (h ? a10 : a00) * inv;
            float g1 = (h ? a11 : a01) * inv;
            float g2 = (h ? a12 : a02) * inv;
            int c0 = 2 * q;
            float v0 = g0 * Wl[c0]      + g1 * Wl[32 + c0]      + g2 * Wl[64 + c0]      + bl[c0];
            float v1 = g0 * Wl[c0 + 1]  + g1 * Wl[32 + c0 + 1]  + g2 * Wl[64 + c0 + 1]  + bl[c0 + 1];
            v0 = v0 > 0.0f ? v0 : __expf(fminf(v0, 0.0f)) - 1.0f;
            v1 = v1 > 0.0f ? v1 : __expf(fminf(v1, 0.0f)) - 1.0f;
            xout[(long)node * 16 + q] = pack_bf16(v0, v1);
        }
    }
}

// ---------------------------------------------------------------------------
// node_transform (R9/R1 proven, node-major). Layers 2-3 only.
// ---------------------------------------------------------------------------
template <int XMODE, int C_IN, int H, int C>
__global__ __launch_bounds__(256) void node_transform(
    const void* __restrict__ xin, const int* __restrict__ flagp,
    const void* __restrict__ W, const void* __restrict__ a_s,
    const void* __restrict__ a_d,
    unsigned* __restrict__ h2, float* __restrict__ als,
    float* __restrict__ ald, int N)
{
    const int bf = *flagp;
    constexpr int HC = H * C;
    __shared__ float Ws[C_IN * HC];
    __shared__ float asS[HC];
    __shared__ float adS[HC];
    for (int i = threadIdx.x; i < C_IN * HC; i += 256) Ws[i] = loadIn(W, i, bf);
    for (int i = threadIdx.x; i < HC; i += 256) {
        asS[i] = loadIn(a_s, i, bf);
        adS[i] = loadIn(a_d, i, bf);
    }
    __syncthreads();

    int n = blockIdx.x * 256 + threadIdx.x;
    if (n >= N) return;

    float xv[C_IN];
    if (XMODE) {
        const uint4* x4 = (const uint4*)xin;
#pragma unroll
        for (int q = 0; q < C_IN / 8; q++) {
            uint4 w = x4[(long)n * (C_IN / 8) + q];
            xv[q * 8 + 0] = lo16(w.x); xv[q * 8 + 1] = hi16(w.x);
            xv[q * 8 + 2] = lo16(w.y); xv[q * 8 + 3] = hi16(w.y);
            xv[q * 8 + 4] = lo16(w.z); xv[q * 8 + 5] = hi16(w.z);
            xv[q * 8 + 6] = lo16(w.w); xv[q * 8 + 7] = hi16(w.w);
        }
    } else {
#pragma unroll
        for (int k = 0; k < C_IN; k++) xv[k] = loadIn(xin, (long)n * C_IN + k, bf);
    }

    float hv[HC];
#pragma unroll
    for (int j = 0; j < HC; j++) {
        float v = 0.0f;
#pragma unroll
        for (int k = 0; k < C_IN; k++) v = fmaf(xv[k], Ws[k * HC + j], v);
        hv[j] = v;
    }
#pragma unroll
    for (int jj = 0; jj < HC / 2; jj++)
        h2[(long)n * (HC / 2) + jj] = pack_bf16(hv[2 * jj], hv[2 * jj + 1]);

#pragma unroll
    for (int hh = 0; hh < H; hh++) {
        float vs = 0.0f, vd = 0.0f;
#pragma unroll
        for (int c = 0; c < C; c++) {
            vs = fmaf(hv[hh * C + c], asS[hh * C + c], vs);
            vd = fmaf(hv[hh * C + c], adS[hh * C + c], vd);
        }
        als[(long)n * H + hh] = vs;
        ald[(long)n * H + hh] = vd;
    }
}

// ---------------------------------------------------------------------------
// aggregate (R22 resubmit; R9 was infra failure, desk-check clean):
// R5 2-deep schedule + exp-dedup edge loop. The remaining fat after R5-R8
// was VALU redundancy: all J lanes of a p-group computed the SAME logit+exp
// chain (~11 VALU/unit, 6 units). New edge loop:
//  - lane l owns edge l: ONE ss load (vs 6), ONE float2 als load covering
//    both heads (vs 6 scalar), exp computed once per edge (2 chains vs 6).
//  - unit loop gets e via __shfl(e0v, p+u*EPW) on the idle DS pipe
//    (SQ_LDS_BANK_CONFLICT=0 all session); per-unit VALU: sel+4fma+add.
//  - h2 gathers UNCHANGED: sr[u] reconstructed by shuffling sv — same
//    addresses, same in-flight set (R6 lesson), straight-line (R7 lesson).
//  - exp values bit-identical to R5 (same fp ops) -> absmax unchanged.
// Pipeline state shrinks ~24 VGPR (av[6]/sr[6] x2 slots -> sv/af x2).
// ---------------------------------------------------------------------------
template <int H, int C, int NCH, int UNR, int FUSE>
__global__ __launch_bounds__(256) void aggregate(
    const int* __restrict__ rp_start, const int* __restrict__ cnt,
    const int* __restrict__ ss,
    const unsigned* __restrict__ h2,
    const float* __restrict__ als, const float* __restrict__ ald,
    const void* __restrict__ bias, const void* __restrict__ Wo,
    const void* __restrict__ bo, const int* __restrict__ flagp,
    void* __restrict__ xout, int N)
{
    constexpr int HC = H * C;
    constexpr int J = HC / NCH;     // lanes per edge row
    constexpr int EPW = 64 / J;     // edge rows per wave
    constexpr int SLOTS = UNR * EPW;
    const int bf = *flagp;
    int lane = threadIdx.x & 63;
    int p = lane / J;
    int j = lane % J;
    int c0 = NCH * j;
    int head = c0 / C;

    float bv[NCH];
#pragma unroll
    for (int i = 0; i < NCH; i++) bv[i] = loadIn(bias, c0 + i, bf);
    float wov[NCH];
    float bov = 0.0f;
    if constexpr (FUSE) {
#pragma unroll
        for (int i = 0; i < NCH; i++) wov[i] = loadIn(Wo, c0 + i, bf);
        bov = loadIn(bo, 0, bf);
    }

    const int nstride = gridDim.x << 2;   // 4 waves per block
    const int node0 = (blockIdx.x << 2) + (threadIdx.x >> 6);
    if (node0 >= N) return;

    // ---- pipeline state: 2 slots, all statically indexed (rule #20)
    int nd0, nd1, st0, st1, dg0, dg1;
    float2 an0, an1, sa0, sa1;            // ald/als both heads (y unused H=1)
    uint2 sq0, sq1; unsigned sw0, sw1;    // self h row fragments
    int sv0, sv1;                         // lane's edge src (edge = lane)
    float2 af0, af1;                      // lane's edge als (both heads)
    uint2 hq0[UNR], hq1[UNR];
    unsigned hw0[UNR], hw1[UNR];

#define AGG_LOADCSR(S, NODE) {                                              \
    int nn_ = (NODE); nd##S = nn_;                                          \
    int ii_ = nn_ < N ? nn_ : N - 1;                                        \
    st##S = rp_start[ii_];                                                  \
    dg##S = nn_ < N ? cnt[ii_] : 0;                                         \
    if constexpr (H == 2) {                                                 \
        an##S = ((const float2*)ald)[ii_];                                  \
        sa##S = ((const float2*)als)[ii_];                                  \
    } else {                                                                \
        an##S.x = ald[ii_]; an##S.y = 0.0f;                                 \
        sa##S.x = als[ii_]; sa##S.y = 0.0f;                                 \
    }                                                                       \
    if constexpr (NCH == 4) sq##S = ((const uint2*)h2)[ii_ * (HC / 4) + j]; \
    else sw##S = h2[ii_ * (HC / 2) + j]; }

#define AGG_ISSUE_SS(S) {                                                   \
    int dm1_ = dg##S > 0 ? dg##S - 1 : 0;                                   \
    int kk_ = (lane < dg##S && lane < SLOTS) ? lane : dm1_;                 \
    sv##S = ss[st##S + kk_]; }

#define AGG_ISSUE_G(S) {                                                    \
    if constexpr (H == 2) af##S = ((const float2*)als)[sv##S];              \
    else { af##S.x = als[sv##S]; af##S.y = 0.0f; }                          \
    _Pragma("unroll") for (int u = 0; u < UNR; u++) {                       \
        int sru_ = __shfl(sv##S, p + u * EPW, 64);                          \
        if constexpr (NCH == 4)                                             \
            hq##S[u] = ((const uint2*)h2)[sru_ * (HC / 4) + j];             \
        else hw##S[u] = h2[sru_ * (HC / 2) + j]; } }

#define AGG_BODY(A, B) {                                                    \
    int node_c = nd##A, start_c = st##A, deg_c = dg##A;                     \
    float2 an_c = an##A, sa_c = sa##A;                                      \
    float2 af_c = af##A;                                                    \
    uint2 sq_c = sq##A; unsigned sw_c = sw##A; (void)sq_c; (void)sw_c;      \
    /* (a) issue gathers for NXT */                                         \
    AGG_ISSUE_G(B);                                                         \
    /* (b) prefetch CSR+self for node_c + 2*nstride into slot A */          \
    AGG_LOADCSR(A, node_c + 2 * nstride);                                   \
    /* (c) compute CUR */                                                   \
    float an_h = (H == 2) ? (head ? an_c.y : an_c.x) : an_c.x;              \
    float sa_h = (H == 2) ? (head ? sa_c.y : sa_c.x) : sa_c.x;              \
    float acc[NCH]; float ssum = 0.0f;                                      \
    _Pragma("unroll") for (int i = 0; i < NCH; i++) acc[i] = 0.0f;          \
    if (p == 0) {                                                           \
        float es_ = __expf(fminf(leaky(sa_h + an_h), 80.0f));               \
        if constexpr (NCH == 4) {                                           \
            acc[0] = lo16(sq_c.x) * es_; acc[1] = hi16(sq_c.x) * es_;       \
            acc[2] = lo16(sq_c.y) * es_; acc[3] = hi16(sq_c.y) * es_;       \
        } else {                                                            \
            acc[0] = lo16(sw_c) * es_; acc[1] = hi16(sw_c) * es_;           \
        }                                                                   \
        ssum = es_;                                                         \
    }                                                                       \
    /* exp phase: lane owns edge=lane, computes e once per head */          \
    bool okl_ = (lane < SLOTS) && (lane < deg_c);                           \
    float e0v_ = okl_                                                       \
        ? __expf(fminf(leaky(af_c.x + an_c.x), 80.0f)) : 0.0f;              \
    float e1v_ = 0.0f;                                                      \
    if constexpr (H == 2)                                                   \
        e1v_ = okl_                                                         \
            ? __expf(fminf(leaky(af_c.y + an_c.y), 80.0f)) : 0.0f;          \
    /* unit loop: e via DS shuffle, VALU = sel + NCH fma + add */           \
    _Pragma("unroll") for (int u = 0; u < UNR; u++) {                       \
        float e_;                                                           \
        if constexpr (H == 2) {                                             \
            float s0_ = __shfl(e0v_, p + u * EPW, 64);                      \
            float s1_ = __shfl(e1v_, p + u * EPW, 64);                      \
            e_ = head ? s1_ : s0_;                                          \
        } else {                                                            \
            e_ = __shfl(e0v_, p + u * EPW, 64);                             \
        }                                                                   \
        if constexpr (NCH == 4) {                                           \
            acc[0] = fmaf(lo16(hq##A[u].x), e_, acc[0]);                    \
            acc[1] = fmaf(hi16(hq##A[u].x), e_, acc[1]);                    \
            acc[2] = fmaf(lo16(hq##A[u].y), e_, acc[2]);                    \
            acc[3] = fmaf(hi16(hq##A[u].y), e_, acc[3]);                    \
        } else {                                                            \
            acc[0] = fmaf(lo16(hw##A[u]), e_, acc[0]);                      \
            acc[1] = fmaf(hi16(hw##A[u]), e_, acc[1]);                      \
        }                                                                   \
        ssum += e_;                                                         \
    }                                                                       \
    /* rare tail: deg > SLOTS (wave-uniform branch, per-lane exp) */        \
    if (deg_c > SLOTS) {                                                    \
        for (int kb_ = SLOTS + p; kb_ < deg_c; kb_ += EPW) {                \
            int s_ = ss[start_c + kb_];                                     \
            float a_ = als[s_ * H + head];                                  \
            float e_ = __expf(fminf(leaky(a_ + an_h), 80.0f));              \
            if constexpr (NCH == 4) {                                       \
                uint2 hv_ = ((const uint2*)h2)[s_ * (HC / 4) + j];          \
                acc[0] = fmaf(lo16(hv_.x), e_, acc[0]);                     \
                acc[1] = fmaf(hi16(hv_.x), e_, acc[1]);                     \
                acc[2] = fmaf(lo16(hv_.y), e_, acc[2]);                     \
                acc[3] = fmaf(hi16(hv_.y), e_, acc[3]);                     \
            } else {                                                        \
                unsigned hv_ = h2[s_ * (HC / 2) + j];                       \
                acc[0] = fmaf(lo16(hv_), e_, acc[0]);                       \
                acc[1] = fmaf(hi16(hv_), e_, acc[1]);                       \
            }                                                               \
            ssum += e_;                                                     \
        }                                                                   \
    }                                                                       \
    /* (e) issue ss for slot A's new node (CSR landed during compute) */    \
    AGG_ISSUE_SS(A);                                                        \
    /* (d) finish CUR */                                                    \
    _Pragma("unroll") for (int off = J; off < 64; off <<= 1) {              \
        _Pragma("unroll") for (int i = 0; i < NCH; i++)                     \
            acc[i] += __shfl_xor(acc[i], off, 64);                          \
        ssum += __shfl_xor(ssum, off, 64);                                  \
    }                                                                       \
    float inv = 1.0f / (ssum + 1e-16f);                                     \
    float v[NCH];                                                           \
    _Pragma("unroll") for (int i = 0; i < NCH; i++) {                       \
        float t_ = acc[i] * inv + bv[i];                                    \
        v[i] = t_ > 0.0f ? t_ : __expf(fminf(t_, 0.0f)) - 1.0f;             \
    }                                                                       \
    if constexpr (FUSE) {                                                   \
        float r_ = 0.0f;                                                    \
        _Pragma("unroll") for (int i = 0; i < NCH; i++)                     \
            r_ = fmaf(v[i], wov[i], r_);                                    \
        _Pragma("unroll") for (int off = 1; off < J; off <<= 1)             \
            r_ += __shfl_xor(r_, off, 64);                                  \
        if (lane == 0 && node_c < N) {                                      \
            r_ += bov;                                                      \
            if (bf) ((__hip_bfloat16*)xout)[node_c] = __float2bfloat16(r_); \
            else    ((float*)xout)[node_c] = r_;                            \
        }                                                                   \
    } else {                                                                \
        if (p == 0 && node_c < N) {                                         \
            if constexpr (NCH == 4) {                                       \
                uint2 o_; o_.x = pack_bf16(v[0], v[1]);                     \
                o_.y = pack_bf16(v[2], v[3]);                               \
                ((uint2*)xout)[node_c * (HC / 4) + j] = o_;                 \
            } else {                                                        \
                ((unsigned*)xout)[node_c * (HC / 2) + j] =                  \
                    pack_bf16(v[0], v[1]);                                  \
            }                                                               \
        }                                                                   \
    } }

    // ---- prologue: fill slots 0 (node0) and 1 (node0+ns)
    AGG_LOADCSR(0, node0);
    AGG_LOADCSR(1, node0 + nstride);
    AGG_ISSUE_SS(0);
    AGG_ISSUE_G(0);
    AGG_ISSUE_SS(1);

    for (;;) {
        AGG_BODY(0, 1);
        if (nd1 >= N) break;
        AGG_BODY(1, 0);
        if (nd0 >= N) break;
    }

#undef AGG_LOADCSR
#undef AGG_ISSUE_SS
#undef AGG_ISSUE_G
#undef AGG_BODY
}

// ---------------------------------------------------------------------------
extern "C" void kernel_launch(void* const* d_in, const int* in_sizes, int n_in,
                              void* d_out, int out_size, void* d_ws, size_t ws_size,
                              hipStream_t stream) {
    const void* x   = d_in[0];
    const int*  ei  = (const int*)d_in[1];
    const void* W1  = d_in[2];
    const void* as1 = d_in[3];
    const void* ad1 = d_in[4];
    const void* b1  = d_in[5];
    const void* W2  = d_in[6];
    const void* as2 = d_in[7];
    const void* ad2 = d_in[8];
    const void* b2  = d_in[9];
    const void* W3  = d_in[10];
    const void* as3 = d_in[11];
    const void* ad3 = d_in[12];
    const void* b3  = d_in[13];
    const void* Wo  = d_in[14];
    const void* bo  = d_in[15];

    const int N = in_sizes[0] / 3;
    const int E = in_sizes[1] / 2;
    const int* ei0 = ei;       // src
    const int* ei1 = ei + E;   // dst

    // ---- ws layout (~29.6 MB @ N=1e5, E=3.2e6; fits <32MB budget)
    int* flag   = (int*)d_ws;              // 64
    int* bcnt   = flag + 64;               // 1024
    int* bstart = bcnt + 1024;             // 1025 (padded 1088)
    int* bcur   = bstart + 1088;           // 1024
    int* cnt    = bcur + 1024;             // N
    int* rp     = cnt + N;                 // N
    int* ss     = rp + N;                  // E  (phase-A buf aliases this)
    float* als  = (float*)(ss + E);        // N*2 (node-major [N][2])
    float* ald  = als + (long)N * 2;       // N*2 (node-major [N][2])
    unsigned* A = (unsigned*)(ald + (long)N * 2); // N*16 u32
    unsigned* h = A + (long)N * 16;               // N*16 u32
    float4* xp  = (float4*)(h + (long)N * 16);    // N float4 (16B rows)
    float* cvec = (float*)(xp + (long)N);         // 12 floats

    const int B = 256;
    auto cdiv = [](long a, long b) { return (int)((a + b - 1) / b); };
    const int NBKT = cdiv(N, 256);   // 256-node buckets (R12)

    // persistent grids: 2048 blocks x 4 waves (grid-stride over nodes)
    const int aggBlocks = 2048;

    // ---- two-level CSR build (dst-sorted), once, reused by all 3 layers
    prep<<<1, 1024, 0, stream>>>((const unsigned*)x, flag, bcnt);
    xprep<<<cdiv(N, B), B, 0, stream>>>(x, flag, W1, as1, ad1, xp, cvec, N);
    bhist<<<256, B, 0, stream>>>(ei1, E, bcnt);
    bscan<<<1, 1024, 0, stream>>>(bcnt, bstart, bcur);
    block_scatter<<<cdiv(E, CS_CHUNK), 512, 0, stream>>>(ei0, ei1, E, bcur, ss);
    fine_scatter<<<NBKT, B, 0, stream>>>(bstart, ss, ss, rp, cnt, N);

    // ---- Layer 1: 3 -> 2x16, commuted form: gather x (16B) only
    aggregate_l1<<<aggBlocks, B, 0, stream>>>(
        rp, cnt, ss, xp, cvec, W1, b1, flag, A, N);

    // ---- Layer 2: 32 -> 2x16 (2-deep pipeline + exp-dedup edge loop)
    node_transform<1, 32, 2, 16><<<cdiv(N, B), B, 0, stream>>>(
        A, flag, W2, as2, ad2, h, als, ald, N);
    aggregate<2, 16, 4, 6, 0><<<aggBlocks, B, 0, stream>>>(
        rp, cnt, ss, h, als, ald, b2, nullptr, nullptr, flag, A, N);

    // ---- Layer 3: 32 -> 1x8, fused output head (same structure)
    node_transform<1, 32, 1, 8><<<cdiv(N, B), B, 0, stream>>>(
        A, flag, W3, as3, ad3, h, als, ald, N);
    aggregate<1, 8, 2, 3, 1><<<aggBlocks, B, 0, stream>>>(
        rp, cnt, ss, h, als, ald, b3, Wo, bo, flag, d_out, N);
}